// Round 1
// baseline (211.859 us; speedup 1.0000x reference)
//
#include <hip/hip_runtime.h>
#include <cstdint>

#define B_   8
#define C_   128
#define IC_  64
#define N_   2048
#define NEGF (-9000000000000000.0f)
#define ROWS 8

// workspace layout (floats)
#define OFF_FT   0              // B*N   = 16384
#define OFF_FP   16384          // B*N   = 16384
#define OFF_VT   32768          // 128
#define OFF_VP   32896          // 128
#define OFF_VB   33024          // 2 (bt, bp)
#define OFF_GX   33792          // B*N*IC = 1048576  (16B aligned)

// ---------------------------------------------------------------------------
// K1: fold cp_w into theta/phi:  vt[c] = sum_o cp_w[o]*theta_w[o][c], etc.
// ---------------------------------------------------------------------------
__global__ void k_prep(const float* __restrict__ theta_w,
                       const float* __restrict__ theta_b,
                       const float* __restrict__ phi_w,
                       const float* __restrict__ phi_b,
                       const float* __restrict__ cp_w,
                       float* __restrict__ ws) {
  int c = threadIdx.x;
  if (c < C_) {
    float at = 0.f, ap = 0.f;
    for (int o = 0; o < IC_; ++o) {
      at += cp_w[o]       * theta_w[o * C_ + c];
      ap += cp_w[IC_ + o] * phi_w[o * C_ + c];
    }
    ws[OFF_VT + c] = at;
    ws[OFF_VP + c] = ap;
  }
  if (c == 0) {
    float bt = 0.f;
    for (int o = 0; o < IC_; ++o) bt += cp_w[o] * theta_b[o];
    ws[OFF_VB + 0] = bt;
  }
  if (c == 1) {
    float bp = 0.f;
    for (int o = 0; o < IC_; ++o) bp += cp_w[IC_ + o] * phi_b[o];
    ws[OFF_VB + 1] = bp;
  }
}

// ---------------------------------------------------------------------------
// K2: g_x[b][n][o] = sum_c g_w[o][c]*x[b][c][n] + g_b[o]   (layout: o fastest)
//     f_t[b][n]    = sum_c vt[c]*x[b][c][n] + bt ; same for f_p
// one block per (b, 64-n tile); 256 threads
// ---------------------------------------------------------------------------
__global__ __launch_bounds__(256) void k_gx(const float* __restrict__ x,
                                            const float* __restrict__ g_w,
                                            const float* __restrict__ g_b,
                                            float* __restrict__ ws) {
  __shared__ float xs[C_][64];     // 32 KB ; xs[c][n]
  __shared__ float wgT[C_][IC_];   // 32 KB ; wgT[c][o]  (transposed -> conflict-free)
  int bx = blockIdx.x;
  int b = bx >> 5, tile = bx & 31;
  int n0 = tile * 64;
  int t = threadIdx.x;

  const float* xb = x + (size_t)b * C_ * N_ + n0;
  for (int idx = t; idx < C_ * 64; idx += 256) {
    int c = idx >> 6, n = idx & 63;
    xs[c][n] = xb[(size_t)c * N_ + n];
  }
  for (int idx = t; idx < C_ * IC_; idx += 256) {
    int c = idx >> 6, o = idx & 63;
    wgT[c][o] = g_w[o * C_ + c];
  }
  __syncthreads();

  int o = t & 63, ngrp = t >> 6;   // each thread: one o, 16 n's
  float acc[16];
#pragma unroll
  for (int k = 0; k < 16; ++k) acc[k] = 0.f;

  for (int c = 0; c < C_; ++c) {
    float wv = wgT[c][o];
    const float* xr = &xs[c][ngrp * 16];
    float4 x0 = *(const float4*)(xr);
    float4 x1 = *(const float4*)(xr + 4);
    float4 x2 = *(const float4*)(xr + 8);
    float4 x3 = *(const float4*)(xr + 12);
    acc[0]  += wv * x0.x; acc[1]  += wv * x0.y; acc[2]  += wv * x0.z; acc[3]  += wv * x0.w;
    acc[4]  += wv * x1.x; acc[5]  += wv * x1.y; acc[6]  += wv * x1.z; acc[7]  += wv * x1.w;
    acc[8]  += wv * x2.x; acc[9]  += wv * x2.y; acc[10] += wv * x2.z; acc[11] += wv * x2.w;
    acc[12] += wv * x3.x; acc[13] += wv * x3.y; acc[14] += wv * x3.z; acc[15] += wv * x3.w;
  }
  float gb = g_b[o];
  float* gx = ws + OFF_GX;
#pragma unroll
  for (int k = 0; k < 16; ++k) {
    gx[((size_t)b * N_ + n0 + ngrp * 16 + k) * IC_ + o] = acc[k] + gb;
  }

  if (t < 64) {  // f_t / f_p for the 64 n's of this tile
    int n = t;
    float ft = ws[OFF_VB + 0], fp = ws[OFF_VB + 1];
    for (int c = 0; c < C_; ++c) {
      float xv = xs[c][n];
      ft += xv * ws[OFF_VT + c];
      fp += xv * ws[OFF_VP + c];
    }
    ws[OFF_FT + b * N_ + n0 + n] = ft;
    ws[OFF_FP + b * N_ + n0 + n] = fp;
  }
}

// ---------------------------------------------------------------------------
// K3: fused attention. Block = (b, 8-row tile), 256 threads.
// Phase 1: P (normalized softmax rows) -> LDS. Phase 2: Y = P * g_x.
// ---------------------------------------------------------------------------
__global__ __launch_bounds__(256) void k_attn(const int* __restrict__ adj,
                                              const float* __restrict__ ws,
                                              float* __restrict__ out) {
  __shared__ float p_s[ROWS][N_];        // 64 KB
  __shared__ float red[4][ROWS][IC_];    // 8 KB
  __shared__ float wredA[4], wredB[4];

  int bx = blockIdx.x;
  int b = bx >> 8, tile = bx & 255;
  int i0 = tile * ROWS;
  int t = threadIdx.x;
  int w = t >> 6, lane = t & 63;

  const float* f_t = ws + OFF_FT + b * N_;
  const float* f_p = ws + OFF_FP + b * N_;
  const float* gx  = ws + OFF_GX + (size_t)b * N_ * IC_;

  // ---- phase 1: softmax rows into p_s ----
  for (int r = 0; r < ROWS; ++r) {
    int i = i0 + r;
    float fti = f_t[i];
    const int* arow = adj + (size_t)i * N_;
    float ev[8];
    float lmax = -3.4e38f;
#pragma unroll
    for (int k = 0; k < 8; ++k) {
      int j = t + k * 256;
      float s = fti + f_p[j];
      s = s > 0.f ? s : 0.2f * s;          // leaky_relu(0.2)
      s = (arow[j] > 0) ? NEGF : s;        // reference masks where adj>0
      ev[k] = s;
      lmax = fmaxf(lmax, s);
    }
#pragma unroll
    for (int off = 32; off > 0; off >>= 1) lmax = fmaxf(lmax, __shfl_xor(lmax, off, 64));
    if (lane == 0) wredA[w] = lmax;
    __syncthreads();
    float bmax = fmaxf(fmaxf(wredA[0], wredA[1]), fmaxf(wredA[2], wredA[3]));

    float lsum = 0.f;
#pragma unroll
    for (int k = 0; k < 8; ++k) {
      float p = __expf(ev[k] - bmax);
      ev[k] = p;
      lsum += p;
    }
#pragma unroll
    for (int off = 32; off > 0; off >>= 1) lsum += __shfl_xor(lsum, off, 64);
    if (lane == 0) wredB[w] = lsum;
    __syncthreads();
    float inv = 1.f / (wredB[0] + wredB[1] + wredB[2] + wredB[3]);
#pragma unroll
    for (int k = 0; k < 8; ++k) p_s[r][t + k * 256] = ev[k] * inv;
  }
  __syncthreads();

  // ---- phase 2: Y[r][o] = sum_j P[r][j] * gx[j][o] ----
  int og = t & 15, jc = t >> 4;   // o-group (16), j-chunk (16 x 128 j)
  int o4 = og * 4;
  float4 y[ROWS];
#pragma unroll
  for (int r = 0; r < ROWS; ++r) y[r] = make_float4(0.f, 0.f, 0.f, 0.f);

  for (int jj = 0; jj < 32; ++jj) {
    int jj2 = (jj + jc) & 31;           // stagger: kills 4-way LDS bank conflict
    int j4 = jc * 128 + jj2 * 4;        // 4 consecutive j
    const float* gp = gx + (size_t)j4 * IC_ + o4;
    float4 g0 = *(const float4*)(gp);
    float4 g1 = *(const float4*)(gp + IC_);
    float4 g2 = *(const float4*)(gp + 2 * IC_);
    float4 g3 = *(const float4*)(gp + 3 * IC_);
#pragma unroll
    for (int r = 0; r < ROWS; ++r) {
      float4 p4 = *(const float4*)&p_s[r][j4];
      y[r].x += p4.x * g0.x + p4.y * g1.x + p4.z * g2.x + p4.w * g3.x;
      y[r].y += p4.x * g0.y + p4.y * g1.y + p4.z * g2.y + p4.w * g3.y;
      y[r].z += p4.x * g0.z + p4.y * g1.z + p4.z * g2.z + p4.w * g3.z;
      y[r].w += p4.x * g0.w + p4.y * g1.w + p4.z * g2.w + p4.w * g3.w;
    }
  }

  // reduce the 4 j-chunks living in this wave (lane bits 4,5)
#pragma unroll
  for (int r = 0; r < ROWS; ++r) {
    y[r].x += __shfl_xor(y[r].x, 16, 64);  y[r].x += __shfl_xor(y[r].x, 32, 64);
    y[r].y += __shfl_xor(y[r].y, 16, 64);  y[r].y += __shfl_xor(y[r].y, 32, 64);
    y[r].z += __shfl_xor(y[r].z, 16, 64);  y[r].z += __shfl_xor(y[r].z, 32, 64);
    y[r].w += __shfl_xor(y[r].w, 16, 64);  y[r].w += __shfl_xor(y[r].w, 32, 64);
  }
  if (((t >> 4) & 3) == 0) {   // one lane-group per wave holds the wave partials
#pragma unroll
    for (int r = 0; r < ROWS; ++r) *(float4*)&red[w][r][o4] = y[r];
  }
  __syncthreads();

  // cross-wave reduce + transposed coalesced store: out[b][o][i0..i0+7]
  if (t < IC_) {
    int o = t;
    float vals[ROWS];
#pragma unroll
    for (int r = 0; r < ROWS; ++r)
      vals[r] = red[0][r][o] + red[1][r][o] + red[2][r][o] + red[3][r][o];
    float* op = out + ((size_t)b * IC_ + o) * N_ + i0;
    *(float4*)(op)     = make_float4(vals[0], vals[1], vals[2], vals[3]);
    *(float4*)(op + 4) = make_float4(vals[4], vals[5], vals[6], vals[7]);
  }
}

// ---------------------------------------------------------------------------
extern "C" void kernel_launch(void* const* d_in, const int* in_sizes, int n_in,
                              void* d_out, int out_size, void* d_ws, size_t ws_size,
                              hipStream_t stream) {
  const float* x       = (const float*)d_in[0];
  const int*   adj     = (const int*)  d_in[1];
  const float* g_w     = (const float*)d_in[2];
  const float* g_b     = (const float*)d_in[3];
  const float* theta_w = (const float*)d_in[4];
  const float* theta_b = (const float*)d_in[5];
  const float* phi_w   = (const float*)d_in[6];
  const float* phi_b   = (const float*)d_in[7];
  const float* cp_w    = (const float*)d_in[8];
  float* out = (float*)d_out;
  float* ws  = (float*)d_ws;

  k_prep<<<1, 128, 0, stream>>>(theta_w, theta_b, phi_w, phi_b, cp_w, ws);
  k_gx<<<B_ * (N_ / 64), 256, 0, stream>>>(x, g_w, g_b, ws);
  k_attn<<<B_ * (N_ / ROWS), 256, 0, stream>>>(adj, ws, out);
}

// Round 2
// 141.595 us; speedup vs baseline: 1.4962x; 1.4962x over previous
//
#include <hip/hip_runtime.h>
#include <hip/hip_bf16.h>
#include <cstdint>

#define B_   8
#define C_   128
#define IC_  64
#define N_   2048
#define NEGF (-9000000000000000.0f)
#define ROWS 16

typedef __attribute__((ext_vector_type(8))) short bf16x8;
typedef __attribute__((ext_vector_type(4))) float f32x4;

// workspace layout (float offsets)
#define OFF_FT   0              // B*N f32
#define OFF_FP   16384          // B*N f32
#define OFF_VT   32768          // 128
#define OFF_VP   32896          // 128
#define OFF_VB   33024          // 2
#define OFF_GXB  33040          // bf16 gxT [B][IC][N] = 2 MB (16B aligned)

static __device__ __forceinline__ ushort f2bf(float f) {
  __hip_bfloat16 h = __float2bfloat16(f);
  return *reinterpret_cast<ushort*>(&h);
}

// ---------------------------------------------------------------------------
// K1: fold cp_w into theta/phi
// ---------------------------------------------------------------------------
__global__ void k_prep(const float* __restrict__ theta_w,
                       const float* __restrict__ theta_b,
                       const float* __restrict__ phi_w,
                       const float* __restrict__ phi_b,
                       const float* __restrict__ cp_w,
                       float* __restrict__ ws) {
  int c = threadIdx.x;
  if (c < C_) {
    float at = 0.f, ap = 0.f;
    for (int o = 0; o < IC_; ++o) {
      at += cp_w[o]       * theta_w[o * C_ + c];
      ap += cp_w[IC_ + o] * phi_w[o * C_ + c];
    }
    ws[OFF_VT + c] = at;
    ws[OFF_VP + c] = ap;
  }
  if (c == 0) {
    float bt = 0.f;
    for (int o = 0; o < IC_; ++o) bt += cp_w[o] * theta_b[o];
    ws[OFF_VB + 0] = bt;
  }
  if (c == 1) {
    float bp = 0.f;
    for (int o = 0; o < IC_; ++o) bp += cp_w[IC_ + o] * phi_b[o];
    ws[OFF_VB + 1] = bp;
  }
}

// ---------------------------------------------------------------------------
// K2: gxT[b][o][n] = bf16( sum_c g_w[o][c]*x[b][c][n] + g_b[o] )  (K-contiguous)
//     f_t[b][n], f_p[b][n] (f32)
// one block per (b, 64-n tile); 256 threads, 4o x 4n register blocking
// ---------------------------------------------------------------------------
__global__ __launch_bounds__(256) void k_gx(const float* __restrict__ x,
                                            const float* __restrict__ g_w,
                                            const float* __restrict__ g_b,
                                            float* __restrict__ ws) {
  __shared__ float xs[C_][64];     // 32 KB
  __shared__ float wgT[C_][IC_];   // 32 KB
  int bx = blockIdx.x;
  int b = bx >> 5, tile = bx & 31;
  int n0 = tile * 64;
  int t = threadIdx.x;

  const float* xb = x + (size_t)b * C_ * N_ + n0;
  for (int idx = t; idx < C_ * 64; idx += 256) {
    int c = idx >> 6, n = idx & 63;
    xs[c][n] = xb[(size_t)c * N_ + n];
  }
  for (int idx = t; idx < C_ * IC_; idx += 256) {
    int c = idx >> 6, o = idx & 63;
    wgT[c][o] = g_w[o * C_ + c];
  }
  __syncthreads();

  int o4 = (t & 15) * 4, n4 = (t >> 4) * 4;
  float acc[4][4] = {};
#pragma unroll 4
  for (int c = 0; c < C_; ++c) {
    float4 xv = *(const float4*)&xs[c][n4];
    float4 wv = *(const float4*)&wgT[c][o4];
    acc[0][0] += wv.x * xv.x; acc[0][1] += wv.x * xv.y; acc[0][2] += wv.x * xv.z; acc[0][3] += wv.x * xv.w;
    acc[1][0] += wv.y * xv.x; acc[1][1] += wv.y * xv.y; acc[1][2] += wv.y * xv.z; acc[1][3] += wv.y * xv.w;
    acc[2][0] += wv.z * xv.x; acc[2][1] += wv.z * xv.y; acc[2][2] += wv.z * xv.z; acc[2][3] += wv.z * xv.w;
    acc[3][0] += wv.w * xv.x; acc[3][1] += wv.w * xv.y; acc[3][2] += wv.w * xv.z; acc[3][3] += wv.w * xv.w;
  }
  __hip_bfloat16* gxT = (__hip_bfloat16*)(ws + OFF_GXB) + (size_t)b * IC_ * N_;
#pragma unroll
  for (int oo = 0; oo < 4; ++oo) {
    float gb = g_b[o4 + oo];
    ushort4 pk = make_ushort4(f2bf(acc[oo][0] + gb), f2bf(acc[oo][1] + gb),
                              f2bf(acc[oo][2] + gb), f2bf(acc[oo][3] + gb));
    *(ushort4*)(gxT + (size_t)(o4 + oo) * N_ + n0 + n4) = pk;
  }

  // f_t (threads 0..63) / f_p (threads 64..127)
  if (t < 128) {
    int n = t & 63;
    int isp = (t >= 64);
    const float* v = ws + (isp ? OFF_VP : OFF_VT);
    float f = ws[OFF_VB + isp];
    for (int c = 0; c < C_; ++c) f += xs[c][n] * v[c];
    ws[(isp ? OFF_FP : OFF_FT) + b * N_ + n0 + n] = f;
  }
}

// ---------------------------------------------------------------------------
// K3: fused attention, MFMA PV. Block = (b, 16-row tile), 256 threads (4 waves).
// Phase 1: barrier-free per-wave softmax rows -> unnormalized bf16 P in
//          XOR-swizzled LDS. Phase 2: wave-sliced K, mfma_f32_16x16x32_bf16,
//          cross-wave reduce via LDS aliased over P (stride 65 = conflict-free).
// ---------------------------------------------------------------------------
__global__ __launch_bounds__(256) void k_attn(const int* __restrict__ adj,
                                              const float* __restrict__ ws,
                                              float* __restrict__ out) {
  __shared__ char smem[ROWS * N_ * 2];   // 64 KB: bf16 P[16][2048]; later f32 red[4][16][65]
  __shared__ float rowsum[ROWS];

  int bx = blockIdx.x;
  int b = bx >> 7, tile = bx & 127;
  int i0 = tile * ROWS;
  int t = threadIdx.x;
  int w = t >> 6, lane = t & 63;

  const float* f_t = ws + OFF_FT + b * N_;
  const float4* fp4 = (const float4*)(ws + OFF_FP + b * N_);
  const __hip_bfloat16* gxT = (const __hip_bfloat16*)(ws + OFF_GXB) + (size_t)b * IC_ * N_;

  float4 fp[8];
#pragma unroll
  for (int kk = 0; kk < 8; ++kk) fp[kk] = fp4[lane + 64 * kk];

  // ---- phase 1: rows w*4 .. w*4+3, lane owns j = 4*lane + 256*kk + {0..3} ----
  for (int rr = 0; rr < 4; ++rr) {
    int r = w * 4 + rr;
    float fti = f_t[i0 + r];
    const int4* arow = (const int4*)(adj + (size_t)(i0 + r) * N_);
    float lsum = 0.f;
#pragma unroll
    for (int kk = 0; kk < 8; ++kk) {
      int4 a = arow[lane + 64 * kk];
      float4 f = fp[kk];
      float sx = fti + f.x; sx = sx > 0.f ? sx : 0.2f * sx; sx = (a.x > 0) ? NEGF : sx;
      float sy = fti + f.y; sy = sy > 0.f ? sy : 0.2f * sy; sy = (a.y > 0) ? NEGF : sy;
      float sz = fti + f.z; sz = sz > 0.f ? sz : 0.2f * sz; sz = (a.z > 0) ? NEGF : sz;
      float sw = fti + f.w; sw = sw > 0.f ? sw : 0.2f * sw; sw = (a.w > 0) ? NEGF : sw;
      float px = __expf(sx), py = __expf(sy), pz = __expf(sz), pw = __expf(sw);
      lsum += (px + py) + (pz + pw);
      ushort4 pk = make_ushort4(f2bf(px), f2bf(py), f2bf(pz), f2bf(pw));
      size_t byte = (size_t)r * 4096 + (size_t)lane * 8 + (size_t)kk * 512;
      byte ^= (size_t)((r & 7) << 4);
      *(ushort4*)(smem + byte) = pk;
    }
#pragma unroll
    for (int off = 32; off; off >>= 1) lsum += __shfl_xor(lsum, off, 64);
    if (lane == 0) rowsum[r] = lsum;
  }
  __syncthreads();

  // ---- phase 2: wave w owns K in [w*512, w*512+512) ----
  f32x4 acc[4];
#pragma unroll
  for (int ot = 0; ot < 4; ++ot) acc[ot] = (f32x4){0.f, 0.f, 0.f, 0.f};
  int arw = lane & 15, agrp = lane >> 4;
  size_t abase = (size_t)arw * 4096 + (size_t)agrp * 16;
  size_t axor = (size_t)((arw & 7) << 4);
  const __hip_bfloat16* gbase = gxT + (size_t)(lane & 15) * N_ + agrp * 8;

  int kw0 = w * 512;
#pragma unroll
  for (int ks = 0; ks < 16; ++ks) {
    int kb = kw0 + ks * 32;
    bf16x8 af = *(const bf16x8*)(smem + ((abase + (size_t)kb * 2) ^ axor));
    const __hip_bfloat16* gp = gbase + kb;
    bf16x8 b0 = *(const bf16x8*)(gp);
    bf16x8 b1 = *(const bf16x8*)(gp + 16 * N_);
    bf16x8 b2 = *(const bf16x8*)(gp + 32 * N_);
    bf16x8 b3 = *(const bf16x8*)(gp + 48 * N_);
    acc[0] = __builtin_amdgcn_mfma_f32_16x16x32_bf16(af, b0, acc[0], 0, 0, 0);
    acc[1] = __builtin_amdgcn_mfma_f32_16x16x32_bf16(af, b1, acc[1], 0, 0, 0);
    acc[2] = __builtin_amdgcn_mfma_f32_16x16x32_bf16(af, b2, acc[2], 0, 0, 0);
    acc[3] = __builtin_amdgcn_mfma_f32_16x16x32_bf16(af, b3, acc[3], 0, 0, 0);
  }
  __syncthreads();   // all P reads done -> safe to alias red over smem

  float* red = (float*)smem;   // [4][16][65] f32 = 16.6 KB
#pragma unroll
  for (int ot = 0; ot < 4; ++ot) {
#pragma unroll
    for (int q = 0; q < 4; ++q) {
      int i = agrp * 4 + q;              // D row = (lane>>4)*4 + reg
      int o = ot * 16 + (lane & 15);     // D col = lane&15
      red[(w * 16 + i) * 65 + o] = acc[ot][q];
    }
  }
  __syncthreads();

  // epilogue: reduce 4 waves, normalize, transposed coalesced store
  int i = t & 15, o0 = t >> 4;
  float inv = 1.f / rowsum[i];
  float* op = out + (size_t)b * IC_ * N_ + i0 + i;
#pragma unroll
  for (int q = 0; q < 4; ++q) {
    int o = o0 + 16 * q;
    float v = red[(0  + i) * 65 + o] + red[(16 + i) * 65 + o]
            + red[(32 + i) * 65 + o] + red[(48 + i) * 65 + o];
    op[(size_t)o * N_] = v * inv;
  }
}

// ---------------------------------------------------------------------------
extern "C" void kernel_launch(void* const* d_in, const int* in_sizes, int n_in,
                              void* d_out, int out_size, void* d_ws, size_t ws_size,
                              hipStream_t stream) {
  const float* x       = (const float*)d_in[0];
  const int*   adj     = (const int*)  d_in[1];
  const float* g_w     = (const float*)d_in[2];
  const float* g_b     = (const float*)d_in[3];
  const float* theta_w = (const float*)d_in[4];
  const float* theta_b = (const float*)d_in[5];
  const float* phi_w   = (const float*)d_in[6];
  const float* phi_b   = (const float*)d_in[7];
  const float* cp_w    = (const float*)d_in[8];
  float* out = (float*)d_out;
  float* ws  = (float*)d_ws;

  k_prep<<<1, 128, 0, stream>>>(theta_w, theta_b, phi_w, phi_b, cp_w, ws);
  k_gx<<<B_ * (N_ / 64), 256, 0, stream>>>(x, g_w, g_b, ws);
  k_attn<<<B_ * (N_ / ROWS), 256, 0, stream>>>(adj, ws, out);
}

// Round 7
// 133.638 us; speedup vs baseline: 1.5853x; 1.0595x over previous
//
#include <hip/hip_runtime.h>
#include <hip/hip_bf16.h>
#include <cstdint>

#define B_    8
#define C_    128
#define IC_   64
#define N_    2048
#define ROWS  16
#define LOG2E 1.44269504088896340736f

typedef __attribute__((ext_vector_type(8))) short bf16x8;
typedef __attribute__((ext_vector_type(4))) float f32x4;

// workspace layout (float offsets)
#define OFF_FT   0          // B*N f32   (pre-scaled by log2e)
#define OFF_FP   16384      // B*N f32   (pre-scaled by log2e)
#define OFF_GXB  32768      // bf16 gxT [B][IC][N] = 2 MB

static __device__ __forceinline__ ushort f2bf(float f) {
  __hip_bfloat16 h = __float2bfloat16(f);
  return *reinterpret_cast<ushort*>(&h);
}

// ---------------------------------------------------------------------------
// K1: gxT[b][o][n] = bf16( sum_c g_w[o][c]*x[b][c][n] + g_b[o] )
//     f_t[b][n], f_p[b][n] (f32, scaled by log2e; cp_w folded in per-block)
// one block per (b, 64-n tile); 256 threads
// ---------------------------------------------------------------------------
__global__ __launch_bounds__(256) void k_gx(const float* __restrict__ x,
                                            const float* __restrict__ g_w,
                                            const float* __restrict__ g_b,
                                            const float* __restrict__ theta_w,
                                            const float* __restrict__ theta_b,
                                            const float* __restrict__ phi_w,
                                            const float* __restrict__ phi_b,
                                            const float* __restrict__ cp_w,
                                            float* __restrict__ ws) {
  __shared__ float xs[C_][64];      // 32 KB
  __shared__ float wgT[C_][IC_];    // 32 KB
  __shared__ float vtp[2][C_];      // 1 KB   (vt, vp)
  __shared__ float fred[2][4][64];  // 2 KB   (ft/fp partials)
  __shared__ float fb[2];
  int bx = blockIdx.x;
  int b = bx >> 5, n0 = (bx & 31) * 64;
  int t = threadIdx.x;

  const float* xb = x + (size_t)b * C_ * N_ + n0;
  for (int idx = t; idx < C_ * 64; idx += 256) {
    int c = idx >> 6, n = idx & 63;
    xs[c][n] = xb[(size_t)c * N_ + n];
  }
  for (int idx = t; idx < C_ * IC_; idx += 256) {
    int c = idx >> 6, o = idx & 63;
    wgT[c][o] = g_w[o * C_ + c];
  }
  // fold cp_w into theta/phi (redundant per block, tiny)
  {
    int half = t >> 7;            // 0: theta, 1: phi
    int c = t & 127;
    const float* wmat = half ? phi_w : theta_w;
    const float* cw = cp_w + half * IC_;
    float a = 0.f;
#pragma unroll 8
    for (int o = 0; o < IC_; ++o) a += cw[o] * wmat[o * C_ + c];
    vtp[half][c] = a * LOG2E;
  }
  if (t < 2) {
    const float* bv = t ? phi_b : theta_b;
    const float* cw = cp_w + t * IC_;
    float a = 0.f;
    for (int o = 0; o < IC_; ++o) a += cw[o] * bv[o];
    fb[t] = a * LOG2E;
  }
  __syncthreads();

  // 4o x 4n register-blocked GEMM
  int o4 = (t & 15) * 4, n4 = (t >> 4) * 4;
  float acc[4][4] = {};
#pragma unroll 4
  for (int c = 0; c < C_; ++c) {
    float4 xv = *(const float4*)&xs[c][n4];
    float4 wv = *(const float4*)&wgT[c][o4];
    acc[0][0] += wv.x * xv.x; acc[0][1] += wv.x * xv.y; acc[0][2] += wv.x * xv.z; acc[0][3] += wv.x * xv.w;
    acc[1][0] += wv.y * xv.x; acc[1][1] += wv.y * xv.y; acc[1][2] += wv.y * xv.z; acc[1][3] += wv.y * xv.w;
    acc[2][0] += wv.z * xv.x; acc[2][1] += wv.z * xv.y; acc[2][2] += wv.z * xv.z; acc[2][3] += wv.z * xv.w;
    acc[3][0] += wv.w * xv.x; acc[3][1] += wv.w * xv.y; acc[3][2] += wv.w * xv.z; acc[3][3] += wv.w * xv.w;
  }
  __hip_bfloat16* gxT = (__hip_bfloat16*)(ws + OFF_GXB) + (size_t)b * IC_ * N_;
#pragma unroll
  for (int oo = 0; oo < 4; ++oo) {
    float gb = g_b[o4 + oo];
    ushort4 pk = make_ushort4(f2bf(acc[oo][0] + gb), f2bf(acc[oo][1] + gb),
                              f2bf(acc[oo][2] + gb), f2bf(acc[oo][3] + gb));
    *(ushort4*)(gxT + (size_t)(o4 + oo) * N_ + n0 + n4) = pk;
  }

  // f tail: 256 threads, 4-way c-split
  {
    int n = t & 63, qr = t >> 6;
    float ft = 0.f, fp = 0.f;
#pragma unroll 8
    for (int cc = 0; cc < 32; ++cc) {
      int c = qr * 32 + cc;
      float xv = xs[c][n];
      ft += xv * vtp[0][c];
      fp += xv * vtp[1][c];
    }
    fred[0][qr][n] = ft;
    fred[1][qr][n] = fp;
  }
  __syncthreads();
  if (t < 128) {
    int n = t & 63, isp = t >> 6;
    float f = fb[isp] + fred[isp][0][n] + fred[isp][1][n]
            + fred[isp][2][n] + fred[isp][3][n];
    ws[(isp ? OFF_FP : OFF_FT) + b * N_ + n0 + n] = f;
  }
}

// ---------------------------------------------------------------------------
// K2: fused attention, chunked flash-style. Block = (b, 16-row tile),
// 256 threads (4 waves). 4 chunks of 512 j: phase 1 = P-chunk (bf16,
// XOR-swizzled) into double-buffered LDS; phase 2 = each wave owns o-tile
// w*16..w*16+15 and MFMA-accumulates over ALL k in registers. One barrier
// per chunk. Row sums held in registers, reduced once at the end.
// ---------------------------------------------------------------------------
__global__ __launch_bounds__(256) void k_attn(const int* __restrict__ adj,
                                              const float* __restrict__ ws,
                                              float* __restrict__ out) {
  __shared__ char pbuf[2][ROWS * 512 * 2];   // 2 x 16 KB
  __shared__ float rowsum[ROWS];

  int bx = blockIdx.x;
  int b = bx >> 7, tile = bx & 127;
  int i0 = tile * ROWS;
  int t = threadIdx.x;
  int w = t >> 6, lane = t & 63;
  int c16 = lane & 15, agrp = lane >> 4;

  const float* f_t = ws + OFF_FT + b * N_;
  const float4* fp4 = (const float4*)(ws + OFF_FP + b * N_);
  const __hip_bfloat16* gxT = (const __hip_bfloat16*)(ws + OFF_GXB) + (size_t)b * IC_ * N_;
  const __hip_bfloat16* gwav = gxT + (size_t)(w * 16 + c16) * N_ + agrp * 8;

  float fti[4];
#pragma unroll
  for (int rr = 0; rr < 4; ++rr) fti[rr] = f_t[i0 + w * 4 + rr];

  float rs[4] = {0.f, 0.f, 0.f, 0.f};
  f32x4 acc = {0.f, 0.f, 0.f, 0.f};

  for (int ch = 0; ch < 4; ++ch) {
    int j0 = ch * 512;
    char* pb = pbuf[ch & 1];
    // lane owns j = j0 + lane*8 .. +7
    float4 fa = fp4[j0 / 4 + lane * 2];
    float4 fbv = fp4[j0 / 4 + lane * 2 + 1];
#pragma unroll
    for (int rr = 0; rr < 4; ++rr) {
      int r = w * 4 + rr;
      const int4* ap = (const int4*)(adj + (size_t)(i0 + r) * N_ + j0) + lane * 2;
      int4 a0 = ap[0], a1 = ap[1];
      float ft = fti[rr];
      float s0 = ft + fa.x;  s0 = fmaxf(s0, 0.2f * s0);
      float s1 = ft + fa.y;  s1 = fmaxf(s1, 0.2f * s1);
      float s2 = ft + fa.z;  s2 = fmaxf(s2, 0.2f * s2);
      float s3 = ft + fa.w;  s3 = fmaxf(s3, 0.2f * s3);
      float s4 = ft + fbv.x; s4 = fmaxf(s4, 0.2f * s4);
      float s5 = ft + fbv.y; s5 = fmaxf(s5, 0.2f * s5);
      float s6 = ft + fbv.z; s6 = fmaxf(s6, 0.2f * s6);
      float s7 = ft + fbv.w; s7 = fmaxf(s7, 0.2f * s7);
      float p0 = (a0.x > 0) ? 0.f : exp2f(s0);
      float p1 = (a0.y > 0) ? 0.f : exp2f(s1);
      float p2 = (a0.z > 0) ? 0.f : exp2f(s2);
      float p3 = (a0.w > 0) ? 0.f : exp2f(s3);
      float p4 = (a1.x > 0) ? 0.f : exp2f(s4);
      float p5 = (a1.y > 0) ? 0.f : exp2f(s5);
      float p6 = (a1.z > 0) ? 0.f : exp2f(s6);
      float p7 = (a1.w > 0) ? 0.f : exp2f(s7);
      rs[rr] += ((p0 + p1) + (p2 + p3)) + ((p4 + p5) + (p6 + p7));
      bf16x8 pk;
      pk[0] = (short)f2bf(p0); pk[1] = (short)f2bf(p1);
      pk[2] = (short)f2bf(p2); pk[3] = (short)f2bf(p3);
      pk[4] = (short)f2bf(p4); pk[5] = (short)f2bf(p5);
      pk[6] = (short)f2bf(p6); pk[7] = (short)f2bf(p7);
      size_t byte = ((size_t)r * 1024 + (size_t)lane * 16) ^ ((size_t)(r & 7) << 4);
      *(bf16x8*)(pb + byte) = pk;
    }
    __syncthreads();
    // phase 2: wave w -> o-cols w*16 + (lane&15); A rows = block rows
#pragma unroll
    for (int ks = 0; ks < 16; ++ks) {
      size_t ab = ((size_t)c16 * 1024 + (size_t)ks * 64 + (size_t)agrp * 16)
                ^ ((size_t)(c16 & 7) << 4);
      bf16x8 af = *(const bf16x8*)(pb + ab);
      bf16x8 bf = *(const bf16x8*)(gwav + j0 + ks * 32);
      acc = __builtin_amdgcn_mfma_f32_16x16x32_bf16(af, bf, acc, 0, 0, 0);
    }
  }

  // row-sum reduce (once)
#pragma unroll
  for (int rr = 0; rr < 4; ++rr) {
    float s = rs[rr];
#pragma unroll
    for (int off = 32; off; off >>= 1) s += __shfl_xor(s, off, 64);
    if (lane == 0) rowsum[w * 4 + rr] = s;
  }
  __syncthreads();

  // epilogue: normalize + store. D row = agrp*4+q, col = c16 (o-tile w*16).
  float4 rsv = *(const float4*)&rowsum[agrp * 4];
  float* op = out + ((size_t)b * IC_ + w * 16 + c16) * N_ + i0 + agrp * 4;
  float4 res = make_float4(acc[0] / rsv.x, acc[1] / rsv.y,
                           acc[2] / rsv.z, acc[3] / rsv.w);
  *(float4*)op = res;
}

// ---------------------------------------------------------------------------
extern "C" void kernel_launch(void* const* d_in, const int* in_sizes, int n_in,
                              void* d_out, int out_size, void* d_ws, size_t ws_size,
                              hipStream_t stream) {
  const float* x       = (const float*)d_in[0];
  const int*   adj     = (const int*)  d_in[1];
  const float* g_w     = (const float*)d_in[2];
  const float* g_b     = (const float*)d_in[3];
  const float* theta_w = (const float*)d_in[4];
  const float* theta_b = (const float*)d_in[5];
  const float* phi_w   = (const float*)d_in[6];
  const float* phi_b   = (const float*)d_in[7];
  const float* cp_w    = (const float*)d_in[8];
  float* out = (float*)d_out;
  float* ws  = (float*)d_ws;

  k_gx<<<B_ * (N_ / 64), 256, 0, stream>>>(x, g_w, g_b, theta_w, theta_b,
                                           phi_w, phi_b, cp_w, ws);
  k_attn<<<B_ * (N_ / ROWS), 256, 0, stream>>>(adj, ws, out);
}